// Round 14
// baseline (132.153 us; speedup 1.0000x reference)
//
#include <hip/hip_runtime.h>
#include <stdint.h>

typedef __bf16 bf16x8 __attribute__((ext_vector_type(8)));
typedef float f32x4 __attribute__((ext_vector_type(4)));
typedef unsigned short ushort_t;
typedef unsigned int uint_t;

__device__ inline ushort_t f2bf(float f) {
  uint_t u = __builtin_bit_cast(uint_t, f);
  u = (u + 0x7FFFu + ((u >> 16) & 1u)) >> 16;
  return (ushort_t)u;
}

// async global->LDS, 16B per lane. LDS dest must be wave-uniform base; HW adds lane*16.
__device__ inline void gll16(const void* g, void* l) {
  __builtin_amdgcn_global_load_lds(
      (__attribute__((address_space(1))) void*)(uintptr_t)g,
      (__attribute__((address_space(3))) void*)(uint32_t)(uintptr_t)l,
      16, 0, 0);
}

__global__ void cast_bf16(const float* __restrict__ in, ushort_t* __restrict__ out,
                          int n4, float scale) {
  int i = blockIdx.x * blockDim.x + threadIdx.x;
  int st = gridDim.x * blockDim.x;
  for (; i < n4; i += st) {
    float4 v = reinterpret_cast<const float4*>(in)[i];
    ushort4 o;
    o.x = f2bf(v.x * scale);
    o.y = f2bf(v.y * scale);
    o.z = f2bf(v.z * scale);
    o.w = f2bf(v.w * scale);
    reinterpret_cast<ushort4*>(out)[i] = o;
  }
}

// All 4 weight matrices in one launch; out = Wq*s | Wk | Wv | Wo contiguous.
__global__ void cast_w4(const float* __restrict__ w0, const float* __restrict__ w1,
                        const float* __restrict__ w2, const float* __restrict__ w3,
                        ushort_t* __restrict__ out, float s0) {
  const int i = blockIdx.x * 256 + threadIdx.x;
  const int which = i >> 18;
  const float* src = which == 0 ? w0 : which == 1 ? w1 : which == 2 ? w2 : w3;
  const float sc = which == 0 ? s0 : 1.0f;
  float4 v = reinterpret_cast<const float4*>(src)[i & 0x3FFFF];
  ushort4 o;
  o.x = f2bf(v.x * sc);
  o.y = f2bf(v.y * sc);
  o.z = f2bf(v.z * sc);
  o.w = f2bf(v.w * sc);
  reinterpret_cast<ushort4*>(out)[i] = o;
}

// ---------------- 8-wave GEMM template: C = A[8192,1024] * B[N,1024]^T
// R12-verified 4-phase schedule. R14: geometry BM=128,BN=128 -> 64KB LDS ->
// 2 independent blocks/CU (m114 implicit overlap covers barrier/wait gaps).
#define MFMA16(A_, B_, C_) __builtin_amdgcn_mfma_f32_16x16x32_bf16(A_, B_, C_, 0, 0, 0)
#define SBAR __builtin_amdgcn_s_barrier
#define LGKM0 asm volatile("s_waitcnt lgkmcnt(0)" ::: "memory")

template <int MF, int NF, int NTN, int LDC, bool F32OUT>
__global__ __launch_bounds__(512, 2) void gemm8p(const ushort_t* __restrict__ A,
                                                 const ushort_t* __restrict__ B,
                                                 void* __restrict__ C) {
  constexpr int BM = MF * 32;
  constexpr int BN = NF * 64;
  constexpr int NA = BM / 64;
  constexpr int NB = BN / 64;
  constexpr int NB0 = (NB >= 2) ? NB / 2 : 1;  // B stage split across ph2/ph3
  constexpr int NG0 = (NF >= 2) ? NF / 2 : 1;  // B reg-group split
  constexpr int AU = BM * 64;
  constexpr int BUF = AU + BN * 64;
  constexpr int NWG = (8192 / BM) * NTN;
  __shared__ __attribute__((aligned(16))) ushort_t smem[2 * BUF];

  const int tid = threadIdx.x;
  const int lane = tid & 63;
  const int w = tid >> 6;
  const int wm = w >> 2, wn = w & 3;

  const int bid = blockIdx.x;
  const int swz = (bid & 7) * (NWG / 8) + (bid >> 3);
  const int m0 = (swz / NTN) * BM;
  const int n0 = (swz % NTN) * BN;

  const int scol = ((tid & 7) ^ ((tid >> 3) & 7)) * 8;
  const ushort_t* gA = A + (size_t)(m0 + (tid >> 3)) * 1024 + scol;
  const ushort_t* gB = B + (size_t)(n0 + (tid >> 3)) * 1024 + scol;

  const int lr = lane & 15;
  const int hi = lane >> 4;
  const int arow = (wm * MF * 16 + lr) * 64;
  const int brow = AU + (wn * NF * 16 + lr) * 64;
  const int cx0 = (hi * 8) ^ ((lane & 7) << 3);
  const int cx1 = cx0 ^ 32;

  f32x4 acc[MF][NF] = {};
  bf16x8 a[MF / 2][2];
  bf16x8 b[NF][2];

  auto stage_a_even = [&](int wbu, int sk) __attribute__((always_inline)) {
    if constexpr (MF == 8) {
      gll16(gA + 0 * 65536 + sk, &smem[wbu + 0 * 4096 + (w << 9)]);
      gll16(gA + 2 * 65536 + sk, &smem[wbu + 2 * 4096 + (w << 9)]);
    } else {
#pragma unroll
      for (int i = 0; i < NA; ++i)
        gll16(gA + i * 65536 + sk, &smem[wbu + i * 4096 + (w << 9)]);
    }
  };
  auto stage_a_odd = [&](int wbu, int sk) __attribute__((always_inline)) {
    if constexpr (MF == 8) {
      gll16(gA + 1 * 65536 + sk, &smem[wbu + 1 * 4096 + (w << 9)]);
      gll16(gA + 3 * 65536 + sk, &smem[wbu + 3 * 4096 + (w << 9)]);
    }
  };
  auto stage_b0 = [&](int wbu, int sk) __attribute__((always_inline)) {
#pragma unroll
    for (int i = 0; i < NB0; ++i)
      gll16(gB + i * 65536 + sk, &smem[wbu + AU + i * 4096 + (w << 9)]);
  };
  auto stage_b1 = [&](int wbu, int sk) __attribute__((always_inline)) {
#pragma unroll
    for (int i = NB0; i < NB; ++i)
      gll16(gB + i * 65536 + sk, &smem[wbu + AU + i * 4096 + (w << 9)]);
  };
  auto rdA = [&](int rbu, int mbase) __attribute__((always_inline)) {
#pragma unroll
    for (int m = 0; m < MF / 2; ++m) {
      const int base = rbu + arow + (mbase + m) * 1024;
      a[m][0] = *(const bf16x8*)&smem[base + cx0];
      a[m][1] = *(const bf16x8*)&smem[base + cx1];
    }
  };
  auto rdBg = [&](int rbu, int ng0, int ng1) __attribute__((always_inline)) {
#pragma unroll
    for (int n = 0; n < NF; ++n) {
      if (n < ng0 || n >= ng1) continue;
      const int base = rbu + brow + n * 1024;
      b[n][0] = *(const bf16x8*)&smem[base + cx0];
      b[n][1] = *(const bf16x8*)&smem[base + cx1];
    }
  };
  auto mmg = [&](int mbase, int ng0, int ng1) __attribute__((always_inline)) {
#pragma unroll
    for (int m = 0; m < MF / 2; ++m)
#pragma unroll
      for (int n = 0; n < NF; ++n) {
        if (n < ng0 || n >= ng1) continue;
        acc[mbase + m][n] = MFMA16(a[m][0], b[n][0], acc[mbase + m][n]);
        acc[mbase + m][n] = MFMA16(a[m][1], b[n][1], acc[mbase + m][n]);
      }
  };

  auto tile = [&](int rbu, int wbu, int sk, bool pf) __attribute__((always_inline)) {
    if (pf) {
      stage_a_even(wbu, sk);
      if constexpr (MF == 8)
        asm volatile("s_waitcnt vmcnt(4)" ::: "memory");
      else
        asm volatile("s_waitcnt vmcnt(2)" ::: "memory");
    } else {
      if constexpr (MF == 8)
        asm volatile("s_waitcnt vmcnt(2)" ::: "memory");
      else
        asm volatile("s_waitcnt vmcnt(0)" ::: "memory");
    }
    SBAR();
    rdA(rbu, 0);
    rdBg(rbu, 0, NG0);
    LGKM0;
    __builtin_amdgcn_s_setprio(1);
    mmg(0, 0, NG0);
    __builtin_amdgcn_s_setprio(0);
    SBAR();
    rdBg(rbu, NG0, NF);
    if (pf) stage_b0(wbu, sk);
    SBAR();
    LGKM0;
    __builtin_amdgcn_s_setprio(1);
    mmg(0, NG0, NF);
    __builtin_amdgcn_s_setprio(0);
    SBAR();
    if (pf) {
      stage_b1(wbu, sk);
      if constexpr (MF == 8)
        asm volatile("s_waitcnt vmcnt(5)" ::: "memory");
    } else {
      if constexpr (MF == 8)
        asm volatile("s_waitcnt vmcnt(0)" ::: "memory");
    }
    SBAR();
    rdA(rbu, MF / 2);
    LGKM0;
    __builtin_amdgcn_s_setprio(1);
    mmg(MF / 2, NG0, NF);
    __builtin_amdgcn_s_setprio(0);
    SBAR();
    if (pf) stage_a_odd(wbu, sk);
    SBAR();
    __builtin_amdgcn_s_setprio(1);
    mmg(MF / 2, 0, NG0);
    __builtin_amdgcn_s_setprio(0);
    SBAR();
  };

  stage_a_even(0, 0);
  stage_b0(0, 0);
  stage_b1(0, 0);
  stage_a_odd(0, 0);
  int sk = 64;
  for (int it = 0; it < 7; ++it) {
    tile(0, BUF, sk, true);
    sk += 64;
    tile(BUF, 0, sk, true);
    sk += 64;
  }
  tile(0, BUF, sk, true);
  tile(BUF, 0, 0, false);

  const size_t erow = (size_t)(m0 + wm * MF * 16 + hi * 4);
  const int ecol = n0 + wn * NF * 16 + lr;
#pragma unroll
  for (int mf = 0; mf < MF; ++mf)
#pragma unroll
    for (int nf = 0; nf < NF; ++nf)
#pragma unroll
      for (int r = 0; r < 4; ++r) {
        const size_t idx = (erow + mf * 16 + r) * LDC + ecol + nf * 16;
        if constexpr (F32OUT)
          ((float*)C)[idx] = acc[mf][nf][r];
        else
          ((ushort_t*)C)[idx] = f2bf(acc[mf][nf][r]);
      }
}

// Causal flash attention (UNCHANGED from R13, passing). QKV [8192,3072] bf16,
// Q pre-scaled by 0.125*log2(e). Merged q-groups, dbuf K/V, cvt_pk P-stores.
__global__ __launch_bounds__(256, 2) void attn_fwd(const ushort_t* __restrict__ QKV,
                                                   ushort_t* __restrict__ ctx) {
  const int bid = blockIdx.x;
  const int h = bid & 15;
  const int b = (bid >> 4) & 7;
  const int p = bid >> 7;  // 0..3
  const int tid = threadIdx.x;
  const int lane = tid & 63;
  const int w = tid >> 6;
  const int lr = lane & 15;
  const int lg = lane >> 4;
  const int dk = lg << 3;

  __shared__ __attribute__((aligned(16))) ushort_t Ks[2][64 * 72];
  __shared__ __attribute__((aligned(16))) uint_t VtDw[2][64 * 36];
  __shared__ __attribute__((aligned(16))) ushort_t Pl[4][32 * 72];

  const int kkey = tid >> 2, kdg = tid & 3;
  const int vkp = tid & 31, vdg = tid >> 5;
  const ushort_t* kgbase =
      QKV + ((size_t)(b * 1024 + kkey)) * 3072 + 1024 + h * 64 + kdg * 16;
  const ushort_t* vgbase =
      QKV + ((size_t)(b * 1024 + 2 * vkp)) * 3072 + 2048 + h * 64 + vdg * 8;

  const float FMAX2 = 23.083120654223414f;  // 16 * log2(e)

  const int qtA = p, qtB = 7 - p;
  const int ntB = (qtB + 1) << 1;
  const int wrow0A = (qtA << 7) + w * 32;
  const int wrow0B = (qtB << 7) + w * 32;

  bf16x8 qfA[2][2], qfB[2][2];
#pragma unroll
  for (int i = 0; i < 2; ++i) {
    const ushort_t* qpA =
        QKV + ((size_t)(b * 1024 + wrow0A + i * 16 + lr)) * 3072 + h * 64 + dk;
    qfA[i][0] = *reinterpret_cast<const bf16x8*>(qpA);
    qfA[i][1] = *reinterpret_cast<const bf16x8*>(qpA + 32);
    const ushort_t* qpB =
        QKV + ((size_t)(b * 1024 + wrow0B + i * 16 + lr)) * 3072 + h * 64 + dk;
    qfB[i][0] = *reinterpret_cast<const bf16x8*>(qpB);
    qfB[i][1] = *reinterpret_cast<const bf16x8*>(qpB + 32);
  }

  f32x4 oA[2][4] = {}, oB[2][4] = {};
  float lsA[2] = {0.f, 0.f}, lsB[2] = {0.f, 0.f};

  uint4 rk0 = *reinterpret_cast<const uint4*>(kgbase);
  uint4 rk1 = *reinterpret_cast<const uint4*>(kgbase + 8);
  uint4 rv0 = *reinterpret_cast<const uint4*>(vgbase);
  uint4 rv1 = *reinterpret_cast<const uint4*>(vgbase + 3072);

  for (int t = 0; t < ntB; ++t) {
    const int bsel = t & 1;
    asm volatile("s_waitcnt vmcnt(0)" ::: "memory");
    {
      uint_t* kd = reinterpret_cast<uint_t*>(&Ks[bsel][kkey * 72 + kdg * 16]);
      *reinterpret_cast<uint4*>(kd) = rk0;
      *reinterpret_cast<uint4*>(kd + 4) = rk1;
      const ushort_t* e0 = reinterpret_cast<const ushort_t*>(&rv0);
      const ushort_t* e1 = reinterpret_cast<const ushort_t*>(&rv1);
#pragma unroll
      for (int j = 0; j < 8; ++j)
        VtDw[bsel][(vdg * 8 + j) * 36 + vkp] = (uint_t)e0[j] | ((uint_t)e1[j] << 16);
    }
    if (t + 1 < ntB) {
      const size_t off = (size_t)(t + 1) * 64 * 3072;
      rk0 = *reinterpret_cast<const uint4*>(kgbase + off);
      rk1 = *reinterpret_cast<const uint4*>(kgbase + off + 8);
      rv0 = *reinterpret_cast<const uint4*>(vgbase + off);
      rv1 = *reinterpret_cast<const uint4*>(vgbase + off + 3072);
    }
    asm volatile("s_waitcnt lgkmcnt(0)" ::: "memory");
    __builtin_amdgcn_s_barrier();

    const int kb = t << 6;
    const bool actB = (kb <= wrow0B + 31);
    const bool actA = (kb <= wrow0A + 31);
    if (!(actA || actB)) continue;

    bf16x8 kf0[4], kf1[4];
#pragma unroll
    for (int f = 0; f < 4; ++f) {
      kf0[f] = *reinterpret_cast<const bf16x8*>(&Ks[bsel][(f * 16 + lr) * 72 + dk]);
      kf1[f] =
          *reinterpret_cast<const bf16x8*>(&Ks[bsel][(f * 16 + lr) * 72 + 32 + dk]);
    }
    bf16x8 vb[2][4];
#pragma unroll
    for (int kblk = 0; kblk < 2; ++kblk)
#pragma unroll
      for (int fh = 0; fh < 4; ++fh)
        vb[kblk][fh] = *reinterpret_cast<const bf16x8*>(
            &VtDw[bsel][(fh * 16 + lr) * 36 + kblk * 16 + (lg << 2)]);

    auto group = [&](const bf16x8(&qf)[2][2], f32x4(&o)[2][4], float(&ls)[2],
                     int wrow0) __attribute__((always_inline)) {
      f32x4 s[2][4];
#pragma unroll
      for (int i = 0; i < 2; ++i)
#pragma unroll
        for (int f = 0; f < 4; ++f) {
          f32x4 z = {0.f, 0.f, 0.f, 0.f};
          z = __builtin_amdgcn_mfma_f32_16x16x32_bf16(kf0[f], qf[i][0], z, 0, 0, 0);
          s[i][f] = __builtin_amdgcn_mfma_f32_16x16x32_bf16(kf1[f], qf[i][1], z, 0, 0, 0);
        }
      const bool needmask = (kb + 63 > wrow0);
#pragma unroll
      for (int i = 0; i < 2; ++i) {
        const int qr = wrow0 + i * 16 + lr;
#pragma unroll
        for (int f = 0; f < 4; ++f) {
          const int kbase = kb + f * 16 + (lg << 2);
          float p0 = __builtin_amdgcn_exp2f(s[i][f][0] - FMAX2);
          float p1 = __builtin_amdgcn_exp2f(s[i][f][1] - FMAX2);
          float p2 = __builtin_amdgcn_exp2f(s[i][f][2] - FMAX2);
          float p3 = __builtin_amdgcn_exp2f(s[i][f][3] - FMAX2);
          if (needmask) {
            p0 = (kbase + 0 <= qr) ? p0 : 0.f;
            p1 = (kbase + 1 <= qr) ? p1 : 0.f;
            p2 = (kbase + 2 <= qr) ? p2 : 0.f;
            p3 = (kbase + 3 <= qr) ? p3 : 0.f;
          }
          ls[i] += (p0 + p1) + (p2 + p3);
          uint_t q01, q23;
          asm("v_cvt_pk_bf16_f32 %0, %1, %2" : "=v"(q01) : "v"(p0), "v"(p1));
          asm("v_cvt_pk_bf16_f32 %0, %1, %2" : "=v"(q23) : "v"(p2), "v"(p3));
          uint2 pk = {q01, q23};
          *reinterpret_cast<uint2*>(
              &Pl[w][(i * 16 + lr) * 72 + f * 16 + (lg << 2)]) = pk;
        }
      }
#pragma unroll
      for (int i = 0; i < 2; ++i)
#pragma unroll
        for (int kblk = 0; kblk < 2; ++kblk) {
          const bf16x8 pa = *reinterpret_cast<const bf16x8*>(
              &Pl[w][(i * 16 + lr) * 72 + kblk * 32 + dk]);
#pragma unroll
          for (int fh = 0; fh < 4; ++fh)
            o[i][fh] = __builtin_amdgcn_mfma_f32_16x16x32_bf16(pa, vb[kblk][fh],
                                                               o[i][fh], 0, 0, 0);
        }
    };

    if (actB) group(qfB, oB, lsB, wrow0B);
    if (actA) group(qfA, oA, lsA, wrow0A);
  }

  auto epi = [&](f32x4(&o)[2][4], float(&ls)[2], int wrow0)
      __attribute__((always_inline)) {
#pragma unroll
    for (int i = 0; i < 2; ++i) {
      float s = ls[i];
      s += __shfl_xor(s, 16);
      s += __shfl_xor(s, 32);
      const float linv = 1.0f / s;
      const size_t crow = (size_t)(b * 1024 + wrow0 + i * 16 + (lg << 2));
#pragma unroll
      for (int r = 0; r < 4; ++r) {
        const float li = __shfl(linv, (lg << 2) + r);
#pragma unroll
        for (int fh = 0; fh < 4; ++fh)
          ctx[(crow + r) * 1024 + h * 64 + fh * 16 + lr] = f2bf(o[i][fh][r] * li);
      }
    }
  };
  epi(oB, lsB, wrow0B);
  epi(oA, lsA, wrow0A);
}

extern "C" void kernel_launch(void* const* d_in, const int* in_sizes, int n_in,
                              void* d_out, int out_size, void* d_ws, size_t ws_size,
                              hipStream_t stream) {
  const float* x = (const float*)d_in[0];
  const float* Wk = (const float*)d_in[1];
  const float* Wq = (const float*)d_in[2];
  const float* Wv = (const float*)d_in[3];
  const float* Wo = (const float*)d_in[4];

  char* ws = (char*)d_ws;
  ushort_t* xb = (ushort_t*)ws;                  // [8192,1024] bf16 (reused as ctx)
  ushort_t* Wc = (ushort_t*)(ws + (16u << 20));  // Wq*0.125*log2e | Wk | Wv | Wo
  ushort_t* Wob = Wc + 3u * 1024 * 1024;
  ushort_t* QKV = (ushort_t*)(ws + (24u << 20));  // [8192,3072] bf16
  ushort_t* ctx = xb;

  cast_bf16<<<2048, 256, 0, stream>>>(x, xb, (8192 * 1024) / 4, 1.0f);
  cast_w4<<<4096, 256, 0, stream>>>(Wq, Wk, Wv, Wo, Wc, 0.125f * 1.4426950408889634f);

  // QKV: BM=128, BN=128 -> 64KB LDS, 2 blocks/CU; grid 1536 = 3 exact generations.
  gemm8p<4, 2, 24, 3072, false><<<1536, 512, 0, stream>>>(xb, Wc, QKV);

  attn_fwd<<<512, 256, 0, stream>>>(QKV, ctx);

  // Out-proj: BM=128, BN=128 -> 512 blocks = 1 exact generation at 2/CU.
  gemm8p<4, 2, 8, 1024, true><<<512, 512, 0, stream>>>(ctx, Wob, (float*)d_out);
}

// Round 15
// 129.238 us; speedup vs baseline: 1.0226x; 1.0226x over previous
//
#include <hip/hip_runtime.h>
#include <stdint.h>

typedef __bf16 bf16x8 __attribute__((ext_vector_type(8)));
typedef float f32x4 __attribute__((ext_vector_type(4)));
typedef unsigned short ushort_t;
typedef unsigned int uint_t;

__device__ inline ushort_t f2bf(float f) {
  uint_t u = __builtin_bit_cast(uint_t, f);
  u = (u + 0x7FFFu + ((u >> 16) & 1u)) >> 16;
  return (ushort_t)u;
}

// async global->LDS, 16B per lane. LDS dest must be wave-uniform base; HW adds lane*16.
__device__ inline void gll16(const void* g, void* l) {
  __builtin_amdgcn_global_load_lds(
      (__attribute__((address_space(1))) void*)(uintptr_t)g,
      (__attribute__((address_space(3))) void*)(uint32_t)(uintptr_t)l,
      16, 0, 0);
}

// One launch: x (2M float4) then Wq|Wk|Wv|Wo (4 x 256K float4). Wq scaled.
__global__ void cast_all(const float* __restrict__ x, const float* __restrict__ w0,
                         const float* __restrict__ w1, const float* __restrict__ w2,
                         const float* __restrict__ w3, ushort_t* __restrict__ xb,
                         ushort_t* __restrict__ wc, float s0) {
  const int i = blockIdx.x * 256 + threadIdx.x;  // 0 .. 3M-1 float4 units
  const float* src;
  ushort_t* dst;
  float sc = 1.0f;
  int j;
  if (i < (1 << 21)) {  // x: 8192*1024 floats = 2M float4
    src = x;
    dst = xb;
    j = i;
  } else {
    const int k = i - (1 << 21);
    const int which = k >> 18;
    src = which == 0 ? w0 : which == 1 ? w1 : which == 2 ? w2 : w3;
    if (which == 0) sc = s0;
    dst = wc + (k >> 18) * (1 << 20);
    j = k & 0x3FFFF;
  }
  float4 v = reinterpret_cast<const float4*>(src)[j];
  ushort4 o;
  o.x = f2bf(v.x * sc);
  o.y = f2bf(v.y * sc);
  o.z = f2bf(v.z * sc);
  o.w = f2bf(v.w * sc);
  reinterpret_cast<ushort4*>(dst)[j] = o;
}

// ---------------- 8-wave GEMM template (R12-verified schedule, R14 template)
#define MFMA16(A_, B_, C_) __builtin_amdgcn_mfma_f32_16x16x32_bf16(A_, B_, C_, 0, 0, 0)
#define SBAR __builtin_amdgcn_s_barrier
#define LGKM0 asm volatile("s_waitcnt lgkmcnt(0)" ::: "memory")

template <int MF, int NF, int NTN, int LDC, bool F32OUT>
__global__ __launch_bounds__(512, 2) void gemm8p(const ushort_t* __restrict__ A,
                                                 const ushort_t* __restrict__ B,
                                                 void* __restrict__ C) {
  constexpr int BM = MF * 32;
  constexpr int BN = NF * 64;
  constexpr int NA = BM / 64;
  constexpr int NB = BN / 64;
  constexpr int NB0 = (NB >= 2) ? NB / 2 : 1;
  constexpr int NG0 = (NF >= 2) ? NF / 2 : 1;
  constexpr int AU = BM * 64;
  constexpr int BUF = AU + BN * 64;
  constexpr int NWG = (8192 / BM) * NTN;
  __shared__ __attribute__((aligned(16))) ushort_t smem[2 * BUF];

  const int tid = threadIdx.x;
  const int lane = tid & 63;
  const int w = tid >> 6;
  const int wm = w >> 2, wn = w & 3;

  const int bid = blockIdx.x;
  const int swz = (bid & 7) * (NWG / 8) + (bid >> 3);
  const int m0 = (swz / NTN) * BM;
  const int n0 = (swz % NTN) * BN;

  const int scol = ((tid & 7) ^ ((tid >> 3) & 7)) * 8;
  const ushort_t* gA = A + (size_t)(m0 + (tid >> 3)) * 1024 + scol;
  const ushort_t* gB = B + (size_t)(n0 + (tid >> 3)) * 1024 + scol;

  const int lr = lane & 15;
  const int hi = lane >> 4;
  const int arow = (wm * MF * 16 + lr) * 64;
  const int brow = AU + (wn * NF * 16 + lr) * 64;
  const int cx0 = (hi * 8) ^ ((lane & 7) << 3);
  const int cx1 = cx0 ^ 32;

  f32x4 acc[MF][NF] = {};
  bf16x8 a[MF / 2][2];
  bf16x8 b[NF][2];

  auto stage_a_even = [&](int wbu, int sk) __attribute__((always_inline)) {
    if constexpr (MF == 8) {
      gll16(gA + 0 * 65536 + sk, &smem[wbu + 0 * 4096 + (w << 9)]);
      gll16(gA + 2 * 65536 + sk, &smem[wbu + 2 * 4096 + (w << 9)]);
    } else {
#pragma unroll
      for (int i = 0; i < NA; ++i)
        gll16(gA + i * 65536 + sk, &smem[wbu + i * 4096 + (w << 9)]);
    }
  };
  auto stage_a_odd = [&](int wbu, int sk) __attribute__((always_inline)) {
    if constexpr (MF == 8) {
      gll16(gA + 1 * 65536 + sk, &smem[wbu + 1 * 4096 + (w << 9)]);
      gll16(gA + 3 * 65536 + sk, &smem[wbu + 3 * 4096 + (w << 9)]);
    }
  };
  auto stage_b0 = [&](int wbu, int sk) __attribute__((always_inline)) {
#pragma unroll
    for (int i = 0; i < NB0; ++i)
      gll16(gB + i * 65536 + sk, &smem[wbu + AU + i * 4096 + (w << 9)]);
  };
  auto stage_b1 = [&](int wbu, int sk) __attribute__((always_inline)) {
#pragma unroll
    for (int i = NB0; i < NB; ++i)
      gll16(gB + i * 65536 + sk, &smem[wbu + AU + i * 4096 + (w << 9)]);
  };
  auto rdA = [&](int rbu, int mbase) __attribute__((always_inline)) {
#pragma unroll
    for (int m = 0; m < MF / 2; ++m) {
      const int base = rbu + arow + (mbase + m) * 1024;
      a[m][0] = *(const bf16x8*)&smem[base + cx0];
      a[m][1] = *(const bf16x8*)&smem[base + cx1];
    }
  };
  auto rdBg = [&](int rbu, int ng0, int ng1) __attribute__((always_inline)) {
#pragma unroll
    for (int n = 0; n < NF; ++n) {
      if (n < ng0 || n >= ng1) continue;
      const int base = rbu + brow + n * 1024;
      b[n][0] = *(const bf16x8*)&smem[base + cx0];
      b[n][1] = *(const bf16x8*)&smem[base + cx1];
    }
  };
  auto mmg = [&](int mbase, int ng0, int ng1) __attribute__((always_inline)) {
#pragma unroll
    for (int m = 0; m < MF / 2; ++m)
#pragma unroll
      for (int n = 0; n < NF; ++n) {
        if (n < ng0 || n >= ng1) continue;
        acc[mbase + m][n] = MFMA16(a[m][0], b[n][0], acc[mbase + m][n]);
        acc[mbase + m][n] = MFMA16(a[m][1], b[n][1], acc[mbase + m][n]);
      }
  };

  auto tile = [&](int rbu, int wbu, int sk, bool pf) __attribute__((always_inline)) {
    if (pf) {
      stage_a_even(wbu, sk);
      if constexpr (MF == 8)
        asm volatile("s_waitcnt vmcnt(4)" ::: "memory");
      else
        asm volatile("s_waitcnt vmcnt(2)" ::: "memory");
    } else {
      if constexpr (MF == 8)
        asm volatile("s_waitcnt vmcnt(2)" ::: "memory");
      else
        asm volatile("s_waitcnt vmcnt(0)" ::: "memory");
    }
    SBAR();
    rdA(rbu, 0);
    rdBg(rbu, 0, NG0);
    LGKM0;
    __builtin_amdgcn_s_setprio(1);
    mmg(0, 0, NG0);
    __builtin_amdgcn_s_setprio(0);
    SBAR();
    rdBg(rbu, NG0, NF);
    if (pf) stage_b0(wbu, sk);
    SBAR();
    LGKM0;
    __builtin_amdgcn_s_setprio(1);
    mmg(0, NG0, NF);
    __builtin_amdgcn_s_setprio(0);
    SBAR();
    if (pf) {
      stage_b1(wbu, sk);
      if constexpr (MF == 8)
        asm volatile("s_waitcnt vmcnt(5)" ::: "memory");
    } else {
      if constexpr (MF == 8)
        asm volatile("s_waitcnt vmcnt(0)" ::: "memory");
    }
    SBAR();
    rdA(rbu, MF / 2);
    LGKM0;
    __builtin_amdgcn_s_setprio(1);
    mmg(MF / 2, NG0, NF);
    __builtin_amdgcn_s_setprio(0);
    SBAR();
    if (pf) stage_a_odd(wbu, sk);
    SBAR();
    __builtin_amdgcn_s_setprio(1);
    mmg(MF / 2, 0, NG0);
    __builtin_amdgcn_s_setprio(0);
    SBAR();
  };

  stage_a_even(0, 0);
  stage_b0(0, 0);
  stage_b1(0, 0);
  stage_a_odd(0, 0);
  int sk = 64;
  for (int it = 0; it < 7; ++it) {
    tile(0, BUF, sk, true);
    sk += 64;
    tile(BUF, 0, sk, true);
    sk += 64;
  }
  tile(0, BUF, sk, true);
  tile(BUF, 0, 0, false);

  const size_t erow = (size_t)(m0 + wm * MF * 16 + hi * 4);
  const int ecol = n0 + wn * NF * 16 + lr;
#pragma unroll
  for (int mf = 0; mf < MF; ++mf)
#pragma unroll
    for (int nf = 0; nf < NF; ++nf)
#pragma unroll
      for (int r = 0; r < 4; ++r) {
        const size_t idx = (erow + mf * 16 + r) * LDC + ecol + nf * 16;
        if constexpr (F32OUT)
          ((float*)C)[idx] = acc[mf][nf][r];
        else
          ((ushort_t*)C)[idx] = f2bf(acc[mf][nf][r]);
      }
}

// Causal flash attention (R13 structure + T5 setprio around MFMA clusters).
__global__ __launch_bounds__(256, 2) void attn_fwd(const ushort_t* __restrict__ QKV,
                                                   ushort_t* __restrict__ ctx) {
  const int bid = blockIdx.x;
  const int h = bid & 15;
  const int b = (bid >> 4) & 7;
  const int p = bid >> 7;  // 0..3
  const int tid = threadIdx.x;
  const int lane = tid & 63;
  const int w = tid >> 6;
  const int lr = lane & 15;
  const int lg = lane >> 4;
  const int dk = lg << 3;

  __shared__ __attribute__((aligned(16))) ushort_t Ks[2][64 * 72];
  __shared__ __attribute__((aligned(16))) uint_t VtDw[2][64 * 36];
  __shared__ __attribute__((aligned(16))) ushort_t Pl[4][32 * 72];

  const int kkey = tid >> 2, kdg = tid & 3;
  const int vkp = tid & 31, vdg = tid >> 5;
  const ushort_t* kgbase =
      QKV + ((size_t)(b * 1024 + kkey)) * 3072 + 1024 + h * 64 + kdg * 16;
  const ushort_t* vgbase =
      QKV + ((size_t)(b * 1024 + 2 * vkp)) * 3072 + 2048 + h * 64 + vdg * 8;

  const float FMAX2 = 23.083120654223414f;  // 16 * log2(e)

  const int qtA = p, qtB = 7 - p;
  const int ntB = (qtB + 1) << 1;
  const int wrow0A = (qtA << 7) + w * 32;
  const int wrow0B = (qtB << 7) + w * 32;

  bf16x8 qfA[2][2], qfB[2][2];
#pragma unroll
  for (int i = 0; i < 2; ++i) {
    const ushort_t* qpA =
        QKV + ((size_t)(b * 1024 + wrow0A + i * 16 + lr)) * 3072 + h * 64 + dk;
    qfA[i][0] = *reinterpret_cast<const bf16x8*>(qpA);
    qfA[i][1] = *reinterpret_cast<const bf16x8*>(qpA + 32);
    const ushort_t* qpB =
        QKV + ((size_t)(b * 1024 + wrow0B + i * 16 + lr)) * 3072 + h * 64 + dk;
    qfB[i][0] = *reinterpret_cast<const bf16x8*>(qpB);
    qfB[i][1] = *reinterpret_cast<const bf16x8*>(qpB + 32);
  }

  f32x4 oA[2][4] = {}, oB[2][4] = {};
  float lsA[2] = {0.f, 0.f}, lsB[2] = {0.f, 0.f};

  uint4 rk0 = *reinterpret_cast<const uint4*>(kgbase);
  uint4 rk1 = *reinterpret_cast<const uint4*>(kgbase + 8);
  uint4 rv0 = *reinterpret_cast<const uint4*>(vgbase);
  uint4 rv1 = *reinterpret_cast<const uint4*>(vgbase + 3072);

  for (int t = 0; t < ntB; ++t) {
    const int bsel = t & 1;
    asm volatile("s_waitcnt vmcnt(0)" ::: "memory");
    {
      uint_t* kd = reinterpret_cast<uint_t*>(&Ks[bsel][kkey * 72 + kdg * 16]);
      *reinterpret_cast<uint4*>(kd) = rk0;
      *reinterpret_cast<uint4*>(kd + 4) = rk1;
      const ushort_t* e0 = reinterpret_cast<const ushort_t*>(&rv0);
      const ushort_t* e1 = reinterpret_cast<const ushort_t*>(&rv1);
#pragma unroll
      for (int j = 0; j < 8; ++j)
        VtDw[bsel][(vdg * 8 + j) * 36 + vkp] = (uint_t)e0[j] | ((uint_t)e1[j] << 16);
    }
    if (t + 1 < ntB) {
      const size_t off = (size_t)(t + 1) * 64 * 3072;
      rk0 = *reinterpret_cast<const uint4*>(kgbase + off);
      rk1 = *reinterpret_cast<const uint4*>(kgbase + off + 8);
      rv0 = *reinterpret_cast<const uint4*>(vgbase + off);
      rv1 = *reinterpret_cast<const uint4*>(vgbase + off + 3072);
    }
    asm volatile("s_waitcnt lgkmcnt(0)" ::: "memory");
    __builtin_amdgcn_s_barrier();

    const int kb = t << 6;
    const bool actB = (kb <= wrow0B + 31);
    const bool actA = (kb <= wrow0A + 31);
    if (!(actA || actB)) continue;

    bf16x8 kf0[4], kf1[4];
#pragma unroll
    for (int f = 0; f < 4; ++f) {
      kf0[f] = *reinterpret_cast<const bf16x8*>(&Ks[bsel][(f * 16 + lr) * 72 + dk]);
      kf1[f] =
          *reinterpret_cast<const bf16x8*>(&Ks[bsel][(f * 16 + lr) * 72 + 32 + dk]);
    }
    bf16x8 vb[2][4];
#pragma unroll
    for (int kblk = 0; kblk < 2; ++kblk)
#pragma unroll
      for (int fh = 0; fh < 4; ++fh)
        vb[kblk][fh] = *reinterpret_cast<const bf16x8*>(
            &VtDw[bsel][(fh * 16 + lr) * 36 + kblk * 16 + (lg << 2)]);

    auto group = [&](const bf16x8(&qf)[2][2], f32x4(&o)[2][4], float(&ls)[2],
                     int wrow0) __attribute__((always_inline)) {
      f32x4 s[2][4];
      __builtin_amdgcn_s_setprio(1);
#pragma unroll
      for (int i = 0; i < 2; ++i)
#pragma unroll
        for (int f = 0; f < 4; ++f) {
          f32x4 z = {0.f, 0.f, 0.f, 0.f};
          z = __builtin_amdgcn_mfma_f32_16x16x32_bf16(kf0[f], qf[i][0], z, 0, 0, 0);
          s[i][f] = __builtin_amdgcn_mfma_f32_16x16x32_bf16(kf1[f], qf[i][1], z, 0, 0, 0);
        }
      __builtin_amdgcn_s_setprio(0);
      const bool needmask = (kb + 63 > wrow0);
#pragma unroll
      for (int i = 0; i < 2; ++i) {
        const int qr = wrow0 + i * 16 + lr;
#pragma unroll
        for (int f = 0; f < 4; ++f) {
          const int kbase = kb + f * 16 + (lg << 2);
          float p0 = __builtin_amdgcn_exp2f(s[i][f][0] - FMAX2);
          float p1 = __builtin_amdgcn_exp2f(s[i][f][1] - FMAX2);
          float p2 = __builtin_amdgcn_exp2f(s[i][f][2] - FMAX2);
          float p3 = __builtin_amdgcn_exp2f(s[i][f][3] - FMAX2);
          if (needmask) {
            p0 = (kbase + 0 <= qr) ? p0 : 0.f;
            p1 = (kbase + 1 <= qr) ? p1 : 0.f;
            p2 = (kbase + 2 <= qr) ? p2 : 0.f;
            p3 = (kbase + 3 <= qr) ? p3 : 0.f;
          }
          ls[i] += (p0 + p1) + (p2 + p3);
          uint_t q01, q23;
          asm("v_cvt_pk_bf16_f32 %0, %1, %2" : "=v"(q01) : "v"(p0), "v"(p1));
          asm("v_cvt_pk_bf16_f32 %0, %1, %2" : "=v"(q23) : "v"(p2), "v"(p3));
          uint2 pk = {q01, q23};
          *reinterpret_cast<uint2*>(
              &Pl[w][(i * 16 + lr) * 72 + f * 16 + (lg << 2)]) = pk;
        }
      }
      __builtin_amdgcn_s_setprio(1);
#pragma unroll
      for (int i = 0; i < 2; ++i)
#pragma unroll
        for (int kblk = 0; kblk < 2; ++kblk) {
          const bf16x8 pa = *reinterpret_cast<const bf16x8*>(
              &Pl[w][(i * 16 + lr) * 72 + kblk * 32 + dk]);
#pragma unroll
          for (int fh = 0; fh < 4; ++fh)
            o[i][fh] = __builtin_amdgcn_mfma_f32_16x16x32_bf16(pa, vb[kblk][fh],
                                                               o[i][fh], 0, 0, 0);
        }
      __builtin_amdgcn_s_setprio(0);
    };

    if (actB) group(qfB, oB, lsB, wrow0B);
    if (actA) group(qfA, oA, lsA, wrow0A);
  }

  auto epi = [&](f32x4(&o)[2][4], float(&ls)[2], int wrow0)
      __attribute__((always_inline)) {
#pragma unroll
    for (int i = 0; i < 2; ++i) {
      float s = ls[i];
      s += __shfl_xor(s, 16);
      s += __shfl_xor(s, 32);
      const float linv = 1.0f / s;
      const size_t crow = (size_t)(b * 1024 + wrow0 + i * 16 + (lg << 2));
#pragma unroll
      for (int r = 0; r < 4; ++r) {
        const float li = __shfl(linv, (lg << 2) + r);
#pragma unroll
        for (int fh = 0; fh < 4; ++fh)
          ctx[(crow + r) * 1024 + h * 64 + fh * 16 + lr] = f2bf(o[i][fh][r] * li);
      }
    }
  };
  epi(oB, lsB, wrow0B);
  epi(oA, lsA, wrow0A);
}

extern "C" void kernel_launch(void* const* d_in, const int* in_sizes, int n_in,
                              void* d_out, int out_size, void* d_ws, size_t ws_size,
                              hipStream_t stream) {
  const float* x = (const float*)d_in[0];
  const float* Wk = (const float*)d_in[1];
  const float* Wq = (const float*)d_in[2];
  const float* Wv = (const float*)d_in[3];
  const float* Wo = (const float*)d_in[4];

  char* ws = (char*)d_ws;
  ushort_t* xb = (ushort_t*)ws;                  // [8192,1024] bf16 (reused as ctx)
  ushort_t* Wc = (ushort_t*)(ws + (16u << 20));  // Wq*0.125*log2e | Wk | Wv | Wo
  ushort_t* Wob = Wc + 3u * 1024 * 1024;
  ushort_t* QKV = (ushort_t*)(ws + (24u << 20));  // [8192,3072] bf16
  ushort_t* ctx = xb;

  // All casts in one launch: 3M float4 units.
  cast_all<<<12288, 256, 0, stream>>>(x, Wq, Wk, Wv, Wo, xb, Wc,
                                      0.125f * 1.4426950408889634f);

  // QKV: BM=256, BN=192 (R12-verified best: high arithmetic intensity).
  gemm8p<8, 3, 16, 3072, false><<<512, 512, 0, stream>>>(xb, Wc, QKV);

  attn_fwd<<<512, 256, 0, stream>>>(QKV, ctx);

  // Out-proj: BM=128, BN=128 (R14-verified best: L2-resident B, 2 blocks/CU).
  gemm8p<4, 2, 8, 1024, true><<<512, 512, 0, stream>>>(ctx, Wob, (float*)d_out);
}

// Round 16
// 125.947 us; speedup vs baseline: 1.0493x; 1.0261x over previous
//
#include <hip/hip_runtime.h>
#include <stdint.h>

typedef __bf16 bf16x8 __attribute__((ext_vector_type(8)));
typedef float f32x4 __attribute__((ext_vector_type(4)));
typedef unsigned short ushort_t;
typedef unsigned int uint_t;

__device__ inline ushort_t f2bf(float f) {
  uint_t u = __builtin_bit_cast(uint_t, f);
  u = (u + 0x7FFFu + ((u >> 16) & 1u)) >> 16;
  return (ushort_t)u;
}

// async global->LDS, 16B per lane. LDS dest must be wave-uniform base; HW adds lane*16.
__device__ inline void gll16(const void* g, void* l) {
  __builtin_amdgcn_global_load_lds(
      (__attribute__((address_space(1))) void*)(uintptr_t)g,
      (__attribute__((address_space(3))) void*)(uint32_t)(uintptr_t)l,
      16, 0, 0);
}

// One launch: x (2M float4) then Wq|Wk|Wv|Wo (4 x 256K float4). Wq scaled.
__global__ void cast_all(const float* __restrict__ x, const float* __restrict__ w0,
                         const float* __restrict__ w1, const float* __restrict__ w2,
                         const float* __restrict__ w3, ushort_t* __restrict__ xb,
                         ushort_t* __restrict__ wc, float s0) {
  const int i = blockIdx.x * 256 + threadIdx.x;  // 0 .. 3M-1 float4 units
  const float* src;
  ushort_t* dst;
  float sc = 1.0f;
  int j;
  if (i < (1 << 21)) {  // x: 8192*1024 floats = 2M float4
    src = x;
    dst = xb;
    j = i;
  } else {
    const int k = i - (1 << 21);
    const int which = k >> 18;
    src = which == 0 ? w0 : which == 1 ? w1 : which == 2 ? w2 : w3;
    if (which == 0) sc = s0;
    dst = wc + (k >> 18) * (1 << 20);
    j = k & 0x3FFFF;
  }
  float4 v = reinterpret_cast<const float4*>(src)[j];
  ushort4 o;
  o.x = f2bf(v.x * sc);
  o.y = f2bf(v.y * sc);
  o.z = f2bf(v.z * sc);
  o.w = f2bf(v.w * sc);
  reinterpret_cast<ushort4*>(dst)[j] = o;
}

// ---------------- 8-wave GEMM template (R12-verified schedule, R14 template)
#define MFMA16(A_, B_, C_) __builtin_amdgcn_mfma_f32_16x16x32_bf16(A_, B_, C_, 0, 0, 0)
#define SBAR __builtin_amdgcn_s_barrier
#define LGKM0 asm volatile("s_waitcnt lgkmcnt(0)" ::: "memory")

template <int MF, int NF, int NTN, int LDC, bool F32OUT>
__global__ __launch_bounds__(512, 2) void gemm8p(const ushort_t* __restrict__ A,
                                                 const ushort_t* __restrict__ B,
                                                 void* __restrict__ C) {
  constexpr int BM = MF * 32;
  constexpr int BN = NF * 64;
  constexpr int NA = BM / 64;
  constexpr int NB = BN / 64;
  constexpr int NB0 = (NB >= 2) ? NB / 2 : 1;
  constexpr int NG0 = (NF >= 2) ? NF / 2 : 1;
  constexpr int AU = BM * 64;
  constexpr int BUF = AU + BN * 64;
  constexpr int NWG = (8192 / BM) * NTN;
  __shared__ __attribute__((aligned(16))) ushort_t smem[2 * BUF];

  const int tid = threadIdx.x;
  const int lane = tid & 63;
  const int w = tid >> 6;
  const int wm = w >> 2, wn = w & 3;

  const int bid = blockIdx.x;
  const int swz = (bid & 7) * (NWG / 8) + (bid >> 3);
  const int m0 = (swz / NTN) * BM;
  const int n0 = (swz % NTN) * BN;

  const int scol = ((tid & 7) ^ ((tid >> 3) & 7)) * 8;
  const ushort_t* gA = A + (size_t)(m0 + (tid >> 3)) * 1024 + scol;
  const ushort_t* gB = B + (size_t)(n0 + (tid >> 3)) * 1024 + scol;

  const int lr = lane & 15;
  const int hi = lane >> 4;
  const int arow = (wm * MF * 16 + lr) * 64;
  const int brow = AU + (wn * NF * 16 + lr) * 64;
  const int cx0 = (hi * 8) ^ ((lane & 7) << 3);
  const int cx1 = cx0 ^ 32;

  f32x4 acc[MF][NF] = {};
  bf16x8 a[MF / 2][2];
  bf16x8 b[NF][2];

  auto stage_a_even = [&](int wbu, int sk) __attribute__((always_inline)) {
    if constexpr (MF == 8) {
      gll16(gA + 0 * 65536 + sk, &smem[wbu + 0 * 4096 + (w << 9)]);
      gll16(gA + 2 * 65536 + sk, &smem[wbu + 2 * 4096 + (w << 9)]);
    } else {
#pragma unroll
      for (int i = 0; i < NA; ++i)
        gll16(gA + i * 65536 + sk, &smem[wbu + i * 4096 + (w << 9)]);
    }
  };
  auto stage_a_odd = [&](int wbu, int sk) __attribute__((always_inline)) {
    if constexpr (MF == 8) {
      gll16(gA + 1 * 65536 + sk, &smem[wbu + 1 * 4096 + (w << 9)]);
      gll16(gA + 3 * 65536 + sk, &smem[wbu + 3 * 4096 + (w << 9)]);
    }
  };
  auto stage_b0 = [&](int wbu, int sk) __attribute__((always_inline)) {
#pragma unroll
    for (int i = 0; i < NB0; ++i)
      gll16(gB + i * 65536 + sk, &smem[wbu + AU + i * 4096 + (w << 9)]);
  };
  auto stage_b1 = [&](int wbu, int sk) __attribute__((always_inline)) {
#pragma unroll
    for (int i = NB0; i < NB; ++i)
      gll16(gB + i * 65536 + sk, &smem[wbu + AU + i * 4096 + (w << 9)]);
  };
  auto rdA = [&](int rbu, int mbase) __attribute__((always_inline)) {
#pragma unroll
    for (int m = 0; m < MF / 2; ++m) {
      const int base = rbu + arow + (mbase + m) * 1024;
      a[m][0] = *(const bf16x8*)&smem[base + cx0];
      a[m][1] = *(const bf16x8*)&smem[base + cx1];
    }
  };
  auto rdBg = [&](int rbu, int ng0, int ng1) __attribute__((always_inline)) {
#pragma unroll
    for (int n = 0; n < NF; ++n) {
      if (n < ng0 || n >= ng1) continue;
      const int base = rbu + brow + n * 1024;
      b[n][0] = *(const bf16x8*)&smem[base + cx0];
      b[n][1] = *(const bf16x8*)&smem[base + cx1];
    }
  };
  auto mmg = [&](int mbase, int ng0, int ng1) __attribute__((always_inline)) {
#pragma unroll
    for (int m = 0; m < MF / 2; ++m)
#pragma unroll
      for (int n = 0; n < NF; ++n) {
        if (n < ng0 || n >= ng1) continue;
        acc[mbase + m][n] = MFMA16(a[m][0], b[n][0], acc[mbase + m][n]);
        acc[mbase + m][n] = MFMA16(a[m][1], b[n][1], acc[mbase + m][n]);
      }
  };

  auto tile = [&](int rbu, int wbu, int sk, bool pf) __attribute__((always_inline)) {
    if (pf) {
      stage_a_even(wbu, sk);
      if constexpr (MF == 8)
        asm volatile("s_waitcnt vmcnt(4)" ::: "memory");
      else
        asm volatile("s_waitcnt vmcnt(2)" ::: "memory");
    } else {
      if constexpr (MF == 8)
        asm volatile("s_waitcnt vmcnt(2)" ::: "memory");
      else
        asm volatile("s_waitcnt vmcnt(0)" ::: "memory");
    }
    SBAR();
    rdA(rbu, 0);
    rdBg(rbu, 0, NG0);
    LGKM0;
    __builtin_amdgcn_s_setprio(1);
    mmg(0, 0, NG0);
    __builtin_amdgcn_s_setprio(0);
    SBAR();
    rdBg(rbu, NG0, NF);
    if (pf) stage_b0(wbu, sk);
    SBAR();
    LGKM0;
    __builtin_amdgcn_s_setprio(1);
    mmg(0, NG0, NF);
    __builtin_amdgcn_s_setprio(0);
    SBAR();
    if (pf) {
      stage_b1(wbu, sk);
      if constexpr (MF == 8)
        asm volatile("s_waitcnt vmcnt(5)" ::: "memory");
    } else {
      if constexpr (MF == 8)
        asm volatile("s_waitcnt vmcnt(0)" ::: "memory");
    }
    SBAR();
    rdA(rbu, MF / 2);
    LGKM0;
    __builtin_amdgcn_s_setprio(1);
    mmg(MF / 2, NG0, NF);
    __builtin_amdgcn_s_setprio(0);
    SBAR();
    if (pf) stage_a_odd(wbu, sk);
    SBAR();
    __builtin_amdgcn_s_setprio(1);
    mmg(MF / 2, 0, NG0);
    __builtin_amdgcn_s_setprio(0);
    SBAR();
  };

  stage_a_even(0, 0);
  stage_b0(0, 0);
  stage_b1(0, 0);
  stage_a_odd(0, 0);
  int sk = 64;
  for (int it = 0; it < 7; ++it) {
    tile(0, BUF, sk, true);
    sk += 64;
    tile(BUF, 0, sk, true);
    sk += 64;
  }
  tile(0, BUF, sk, true);
  tile(BUF, 0, 0, false);

  const size_t erow = (size_t)(m0 + wm * MF * 16 + hi * 4);
  const int ecol = n0 + wn * NF * 16 + lr;
#pragma unroll
  for (int mf = 0; mf < MF; ++mf)
#pragma unroll
    for (int nf = 0; nf < NF; ++nf)
#pragma unroll
      for (int r = 0; r < 4; ++r) {
        const size_t idx = (erow + mf * 16 + r) * LDC + ecol + nf * 16;
        if constexpr (F32OUT)
          ((float*)C)[idx] = acc[mf][nf][r];
        else
          ((ushort_t*)C)[idx] = f2bf(acc[mf][nf][r]);
      }
}

// Causal flash attention. QKV [8192,3072] bf16 (Q|K|V), Q pre-scaled by 0.125*log2(e).
// R16: V staged in PERMUTED key-slot order so the PV A-fragment is assembled
// directly from the cvt_pk outputs (no P LDS round-trip, Pl deleted).
// Slot s holds key 32*kblk + 16*((s&4)!=0) + 4*(s>>3) + (s&3)  [within kblk].
__global__ __launch_bounds__(256, 2) void attn_fwd(const ushort_t* __restrict__ QKV,
                                                   ushort_t* __restrict__ ctx) {
  const int bid = blockIdx.x;
  const int h = bid & 15;
  const int b = (bid >> 4) & 7;
  const int p = bid >> 7;  // 0..3
  const int tid = threadIdx.x;
  const int lane = tid & 63;
  const int w = tid >> 6;
  const int lr = lane & 15;
  const int lg = lane >> 4;
  const int dk = lg << 3;

  __shared__ __attribute__((aligned(16))) ushort_t Ks[2][64 * 72];
  __shared__ __attribute__((aligned(16))) uint_t VtDw[2][64 * 36];

  const int kkey = tid >> 2, kdg = tid & 3;
  const int vkp = tid & 31, vdg = tid >> 5;
  // permuted key-pair slot: pkp = pi(2*vkp)/2 (pairs stay adjacent under pi)
  const int pkp = ((vkp >> 4) << 4) | (((vkp >> 1) & 3) << 2) |
                  (((vkp >> 3) & 1) << 1) | (vkp & 1);
  const ushort_t* kgbase =
      QKV + ((size_t)(b * 1024 + kkey)) * 3072 + 1024 + h * 64 + kdg * 16;
  const ushort_t* vgbase =
      QKV + ((size_t)(b * 1024 + 2 * vkp)) * 3072 + 2048 + h * 64 + vdg * 8;

  const float FMAX2 = 23.083120654223414f;  // 16 * log2(e)

  const int qtA = p, qtB = 7 - p;
  const int ntB = (qtB + 1) << 1;
  const int wrow0A = (qtA << 7) + w * 32;
  const int wrow0B = (qtB << 7) + w * 32;

  bf16x8 qfA[2][2], qfB[2][2];
#pragma unroll
  for (int i = 0; i < 2; ++i) {
    const ushort_t* qpA =
        QKV + ((size_t)(b * 1024 + wrow0A + i * 16 + lr)) * 3072 + h * 64 + dk;
    qfA[i][0] = *reinterpret_cast<const bf16x8*>(qpA);
    qfA[i][1] = *reinterpret_cast<const bf16x8*>(qpA + 32);
    const ushort_t* qpB =
        QKV + ((size_t)(b * 1024 + wrow0B + i * 16 + lr)) * 3072 + h * 64 + dk;
    qfB[i][0] = *reinterpret_cast<const bf16x8*>(qpB);
    qfB[i][1] = *reinterpret_cast<const bf16x8*>(qpB + 32);
  }

  f32x4 oA[2][4] = {}, oB[2][4] = {};
  float lsA[2] = {0.f, 0.f}, lsB[2] = {0.f, 0.f};

  uint4 rk0 = *reinterpret_cast<const uint4*>(kgbase);
  uint4 rk1 = *reinterpret_cast<const uint4*>(kgbase + 8);
  uint4 rv0 = *reinterpret_cast<const uint4*>(vgbase);
  uint4 rv1 = *reinterpret_cast<const uint4*>(vgbase + 3072);

  for (int t = 0; t < ntB; ++t) {
    const int bsel = t & 1;
    asm volatile("s_waitcnt vmcnt(0)" ::: "memory");
    {
      uint_t* kd = reinterpret_cast<uint_t*>(&Ks[bsel][kkey * 72 + kdg * 16]);
      *reinterpret_cast<uint4*>(kd) = rk0;
      *reinterpret_cast<uint4*>(kd + 4) = rk1;
      const ushort_t* e0 = reinterpret_cast<const ushort_t*>(&rv0);
      const ushort_t* e1 = reinterpret_cast<const ushort_t*>(&rv1);
#pragma unroll
      for (int j = 0; j < 8; ++j)
        VtDw[bsel][(vdg * 8 + j) * 36 + pkp] = (uint_t)e0[j] | ((uint_t)e1[j] << 16);
    }
    if (t + 1 < ntB) {
      const size_t off = (size_t)(t + 1) * 64 * 3072;
      rk0 = *reinterpret_cast<const uint4*>(kgbase + off);
      rk1 = *reinterpret_cast<const uint4*>(kgbase + off + 8);
      rv0 = *reinterpret_cast<const uint4*>(vgbase + off);
      rv1 = *reinterpret_cast<const uint4*>(vgbase + off + 3072);
    }
    asm volatile("s_waitcnt lgkmcnt(0)" ::: "memory");
    __builtin_amdgcn_s_barrier();

    const int kb = t << 6;
    const bool actB = (kb <= wrow0B + 31);
    const bool actA = (kb <= wrow0A + 31);
    if (!(actA || actB)) continue;

    bf16x8 kf0[4], kf1[4];
#pragma unroll
    for (int f = 0; f < 4; ++f) {
      kf0[f] = *reinterpret_cast<const bf16x8*>(&Ks[bsel][(f * 16 + lr) * 72 + dk]);
      kf1[f] =
          *reinterpret_cast<const bf16x8*>(&Ks[bsel][(f * 16 + lr) * 72 + 32 + dk]);
    }
    bf16x8 vb[2][4];
#pragma unroll
    for (int kblk = 0; kblk < 2; ++kblk)
#pragma unroll
      for (int fh = 0; fh < 4; ++fh)
        vb[kblk][fh] = *reinterpret_cast<const bf16x8*>(
            &VtDw[bsel][(fh * 16 + lr) * 36 + kblk * 16 + (lg << 2)]);

    auto group = [&](const bf16x8(&qf)[2][2], f32x4(&o)[2][4], float(&ls)[2],
                     int wrow0) __attribute__((always_inline)) {
      f32x4 s[2][4];
      __builtin_amdgcn_s_setprio(1);
#pragma unroll
      for (int i = 0; i < 2; ++i)
#pragma unroll
        for (int f = 0; f < 4; ++f) {
          f32x4 z = {0.f, 0.f, 0.f, 0.f};
          z = __builtin_amdgcn_mfma_f32_16x16x32_bf16(kf0[f], qf[i][0], z, 0, 0, 0);
          s[i][f] = __builtin_amdgcn_mfma_f32_16x16x32_bf16(kf1[f], qf[i][1], z, 0, 0, 0);
        }
      __builtin_amdgcn_s_setprio(0);
      const bool needmask = (kb + 63 > wrow0);
#pragma unroll
      for (int i = 0; i < 2; ++i) {
        const int qr = wrow0 + i * 16 + lr;
        uint_t d0[4], d1[4];
#pragma unroll
        for (int f = 0; f < 4; ++f) {
          const int kbase = kb + f * 16 + (lg << 2);
          float p0 = __builtin_amdgcn_exp2f(s[i][f][0] - FMAX2);
          float p1 = __builtin_amdgcn_exp2f(s[i][f][1] - FMAX2);
          float p2 = __builtin_amdgcn_exp2f(s[i][f][2] - FMAX2);
          float p3 = __builtin_amdgcn_exp2f(s[i][f][3] - FMAX2);
          if (needmask) {
            p0 = (kbase + 0 <= qr) ? p0 : 0.f;
            p1 = (kbase + 1 <= qr) ? p1 : 0.f;
            p2 = (kbase + 2 <= qr) ? p2 : 0.f;
            p3 = (kbase + 3 <= qr) ? p3 : 0.f;
          }
          ls[i] += (p0 + p1) + (p2 + p3);
          asm("v_cvt_pk_bf16_f32 %0, %1, %2" : "=v"(d0[f]) : "v"(p0), "v"(p1));
          asm("v_cvt_pk_bf16_f32 %0, %1, %2" : "=v"(d1[f]) : "v"(p2), "v"(p3));
        }
        // PV for this i: pa assembled in-reg; V slot order matches by construction.
        __builtin_amdgcn_s_setprio(1);
#pragma unroll
        for (int kblk = 0; kblk < 2; ++kblk) {
          uint4 paw;
          paw.x = d0[2 * kblk];
          paw.y = d1[2 * kblk];
          paw.z = d0[2 * kblk + 1];
          paw.w = d1[2 * kblk + 1];
          const bf16x8 pa = __builtin_bit_cast(bf16x8, paw);
#pragma unroll
          for (int fh = 0; fh < 4; ++fh)
            o[i][fh] = __builtin_amdgcn_mfma_f32_16x16x32_bf16(pa, vb[kblk][fh],
                                                               o[i][fh], 0, 0, 0);
        }
        __builtin_amdgcn_s_setprio(0);
      }
    };

    if (actB) group(qfB, oB, lsB, wrow0B);
    if (actA) group(qfA, oA, lsA, wrow0A);
  }

  auto epi = [&](f32x4(&o)[2][4], float(&ls)[2], int wrow0)
      __attribute__((always_inline)) {
#pragma unroll
    for (int i = 0; i < 2; ++i) {
      float s = ls[i];
      s += __shfl_xor(s, 16);
      s += __shfl_xor(s, 32);
      const float linv = 1.0f / s;
      const size_t crow = (size_t)(b * 1024 + wrow0 + i * 16 + (lg << 2));
#pragma unroll
      for (int r = 0; r < 4; ++r) {
        const float li = __shfl(linv, (lg << 2) + r);
#pragma unroll
        for (int fh = 0; fh < 4; ++fh)
          ctx[(crow + r) * 1024 + h * 64 + fh * 16 + lr] = f2bf(o[i][fh][r] * li);
      }
    }
  };
  epi(oB, lsB, wrow0B);
  epi(oA, lsA, wrow0A);
}

extern "C" void kernel_launch(void* const* d_in, const int* in_sizes, int n_in,
                              void* d_out, int out_size, void* d_ws, size_t ws_size,
                              hipStream_t stream) {
  const float* x = (const float*)d_in[0];
  const float* Wk = (const float*)d_in[1];
  const float* Wq = (const float*)d_in[2];
  const float* Wv = (const float*)d_in[3];
  const float* Wo = (const float*)d_in[4];

  char* ws = (char*)d_ws;
  ushort_t* xb = (ushort_t*)ws;                  // [8192,1024] bf16 (reused as ctx)
  ushort_t* Wc = (ushort_t*)(ws + (16u << 20));  // Wq*0.125*log2e | Wk | Wv | Wo
  ushort_t* Wob = Wc + 3u * 1024 * 1024;
  ushort_t* QKV = (ushort_t*)(ws + (24u << 20));  // [8192,3072] bf16
  ushort_t* ctx = xb;

  // All casts in one launch: 3M float4 units.
  cast_all<<<12288, 256, 0, stream>>>(x, Wq, Wk, Wv, Wo, xb, Wc,
                                      0.125f * 1.4426950408889634f);

  // QKV: BM=256, BN=192 (R12-verified best: high arithmetic intensity).
  gemm8p<8, 3, 16, 3072, false><<<512, 512, 0, stream>>>(xb, Wc, QKV);

  attn_fwd<<<512, 256, 0, stream>>>(QKV, ctx);

  // Out-proj: BM=128, BN=128 (R14-verified best: L2-resident B, 2 blocks/CU).
  gemm8p<4, 2, 8, 1024, true><<<512, 512, 0, stream>>>(ctx, Wob, (float*)d_out);
}

// Round 17
// 123.253 us; speedup vs baseline: 1.0722x; 1.0219x over previous
//
#include <hip/hip_runtime.h>
#include <stdint.h>

typedef __bf16 bf16x8 __attribute__((ext_vector_type(8)));
typedef float f32x4 __attribute__((ext_vector_type(4)));
typedef unsigned short ushort_t;
typedef unsigned int uint_t;

__device__ inline ushort_t f2bf(float f) {
  uint_t u = __builtin_bit_cast(uint_t, f);
  u = (u + 0x7FFFu + ((u >> 16) & 1u)) >> 16;
  return (ushort_t)u;
}

// async global->LDS, 16B per lane. LDS dest must be wave-uniform base; HW adds lane*16.
__device__ inline void gll16(const void* g, void* l) {
  __builtin_amdgcn_global_load_lds(
      (__attribute__((address_space(1))) void*)(uintptr_t)g,
      (__attribute__((address_space(3))) void*)(uint32_t)(uintptr_t)l,
      16, 0, 0);
}

// One launch: x (2M float4) then Wq|Wk|Wv|Wo (4 x 256K float4). Wq scaled.
__global__ void cast_all(const float* __restrict__ x, const float* __restrict__ w0,
                         const float* __restrict__ w1, const float* __restrict__ w2,
                         const float* __restrict__ w3, ushort_t* __restrict__ xb,
                         ushort_t* __restrict__ wc, float s0) {
  const int i = blockIdx.x * 256 + threadIdx.x;  // 0 .. 3M-1 float4 units
  const float* src;
  ushort_t* dst;
  float sc = 1.0f;
  int j;
  if (i < (1 << 21)) {  // x: 8192*1024 floats = 2M float4
    src = x;
    dst = xb;
    j = i;
  } else {
    const int k = i - (1 << 21);
    const int which = k >> 18;
    src = which == 0 ? w0 : which == 1 ? w1 : which == 2 ? w2 : w3;
    if (which == 0) sc = s0;
    dst = wc + (k >> 18) * (1 << 20);
    j = k & 0x3FFFF;
  }
  float4 v = reinterpret_cast<const float4*>(src)[j];
  ushort4 o;
  o.x = f2bf(v.x * sc);
  o.y = f2bf(v.y * sc);
  o.z = f2bf(v.z * sc);
  o.w = f2bf(v.w * sc);
  reinterpret_cast<ushort4*>(dst)[j] = o;
}

// ---------------- 8-wave GEMM template: C = A[8192,1024] * B[N,1024]^T
// R17: LDS-read/MFMA OVERLAP. One barrier per K-tile; all ds_reads issued up
// front as compiler-visible loads (compiler emits minimal counted lgkmcnt, so
// set_B (a1) completes DURING MFMA of set_A). All staging at tile top, single
// vmcnt(0) at tile end (full-tile latency coverage). Hazards: all reads of buf R
// retire before SBAR(t) (compiler waits before MFMA); R re-staged only after
// SBAR(t); stage->W drained (vmcnt) before SBAR(t), W read after. [R12 invariant]
#define MFMA16(A_, B_, C_) __builtin_amdgcn_mfma_f32_16x16x32_bf16(A_, B_, C_, 0, 0, 0)
#define SBAR __builtin_amdgcn_s_barrier
#define SCHED0 __builtin_amdgcn_sched_barrier(0)

template <int MF, int NF, int NTN, int LDC, bool F32OUT>
__global__ __launch_bounds__(512, 2) void gemm8p(const ushort_t* __restrict__ A,
                                                 const ushort_t* __restrict__ B,
                                                 void* __restrict__ C) {
  constexpr int BM = MF * 32;
  constexpr int BN = NF * 64;
  constexpr int NA = BM / 64;        // gll16 per thread for A-tile
  constexpr int NB = BN / 64;        // gll16 per thread for B-tile
  constexpr int AU = BM * 64;        // u16 per A buffer
  constexpr int BUF = AU + BN * 64;  // u16 per (A|B) buffer
  constexpr int NWG = (8192 / BM) * NTN;
  __shared__ __attribute__((aligned(16))) ushort_t smem[2 * BUF];

  const int tid = threadIdx.x;
  const int lane = tid & 63;
  const int w = tid >> 6;
  const int wm = w >> 2, wn = w & 3;

  // XCD-aware bijective swizzle (NWG % 8 == 0), row-major tiles.
  const int bid = blockIdx.x;
  const int swz = (bid & 7) * (NWG / 8) + (bid >> 3);
  const int m0 = (swz / NTN) * BM;
  const int n0 = (swz % NTN) * BN;

  // staging: thread covers row (tid>>3), phys 16B chunk (tid&7); source col
  // pre-swizzled so phys LDS stays linear (rule #21: same involution both sides).
  const int scol = ((tid & 7) ^ ((tid >> 3) & 7)) * 8;
  const ushort_t* gA = A + (size_t)(m0 + (tid >> 3)) * 1024 + scol;
  const ushort_t* gB = B + (size_t)(n0 + (tid >> 3)) * 1024 + scol;

  // read offsets (u16 units): row*64 + ((k-chunk)*8 ^ (row&7)*8)
  const int lr = lane & 15;
  const int hi = lane >> 4;
  const int arow = (wm * MF * 16 + lr) * 64;
  const int brow = AU + (wn * NF * 16 + lr) * 64;
  const int cx0 = (hi * 8) ^ ((lane & 7) << 3);
  const int cx1 = cx0 ^ 32;

  f32x4 acc[MF][NF] = {};
  bf16x8 a0[MF / 2][2], a1[MF / 2][2];  // two m-half register sets (pipelined)
  bf16x8 b[NF][2];

  auto stage_all = [&](int wbu, int sk) __attribute__((always_inline)) {
#pragma unroll
    for (int i = 0; i < NA; ++i)
      gll16(gA + i * 65536 + sk, &smem[wbu + i * 4096 + (w << 9)]);
#pragma unroll
    for (int i = 0; i < NB; ++i)
      gll16(gB + i * 65536 + sk, &smem[wbu + AU + i * 4096 + (w << 9)]);
  };
  auto rdA = [&](int rbu, int mbase, bf16x8(&aa)[MF / 2][2])
      __attribute__((always_inline)) {
#pragma unroll
    for (int m = 0; m < MF / 2; ++m) {
      const int base = rbu + arow + (mbase + m) * 1024;
      aa[m][0] = *(const bf16x8*)&smem[base + cx0];
      aa[m][1] = *(const bf16x8*)&smem[base + cx1];
    }
  };
  auto rdBall = [&](int rbu) __attribute__((always_inline)) {
#pragma unroll
    for (int n = 0; n < NF; ++n) {
      const int base = rbu + brow + n * 1024;
      b[n][0] = *(const bf16x8*)&smem[base + cx0];
      b[n][1] = *(const bf16x8*)&smem[base + cx1];
    }
  };
  auto mmH = [&](int mbase, bf16x8(&aa)[MF / 2][2]) __attribute__((always_inline)) {
#pragma unroll
    for (int m = 0; m < MF / 2; ++m)
#pragma unroll
      for (int n = 0; n < NF; ++n) {
        acc[mbase + m][n] = MFMA16(aa[m][0], b[n][0], acc[mbase + m][n]);
        acc[mbase + m][n] = MFMA16(aa[m][1], b[n][1], acc[mbase + m][n]);
      }
  };

  // One K-tile: issue ALL reads (set_A = a0+b, set_B = a1) + ALL staging up
  // front; compiler emits counted lgkmcnt so set_B overlaps MFMA_A. One barrier.
  auto tile = [&](int rbu, int wbu, int sk, bool pf) __attribute__((always_inline)) {
    rdA(rbu, 0, a0);
    rdBall(rbu);
    if (pf) stage_all(wbu, sk);
    rdA(rbu, MF / 2, a1);
    SCHED0;
    __builtin_amdgcn_s_setprio(1);
    mmH(0, a0);  // compiler waits lgkmcnt(|set_B|) here — set_B stays in flight
    __builtin_amdgcn_s_setprio(0);
    SCHED0;
    __builtin_amdgcn_s_setprio(1);
    mmH(MF / 2, a1);  // compiler waits remaining lgkm — covered by MFMA_A
    __builtin_amdgcn_s_setprio(0);
    SCHED0;
    if (pf) asm volatile("s_waitcnt vmcnt(0)" ::: "memory");  // tile t+1 landed
    SBAR();
    SCHED0;
  };

  stage_all(0, 0);
  asm volatile("s_waitcnt vmcnt(0)" ::: "memory");
  SBAR();
  SCHED0;
  int sk = 64;
  for (int it = 0; it < 7; ++it) {
    tile(0, BUF, sk, true);
    sk += 64;
    tile(BUF, 0, sk, true);
    sk += 64;
  }
  tile(0, BUF, sk, true);   // t=14 stages tile 15
  tile(BUF, 0, 0, false);   // t=15: drain

  const size_t erow = (size_t)(m0 + wm * MF * 16 + hi * 4);
  const int ecol = n0 + wn * NF * 16 + lr;
#pragma unroll
  for (int mf = 0; mf < MF; ++mf)
#pragma unroll
    for (int nf = 0; nf < NF; ++nf)
#pragma unroll
      for (int r = 0; r < 4; ++r) {
        const size_t idx = (erow + mf * 16 + r) * LDC + ecol + nf * 16;
        if constexpr (F32OUT)
          ((float*)C)[idx] = acc[mf][nf][r];
        else
          ((ushort_t*)C)[idx] = f2bf(acc[mf][nf][r]);
      }
}

// Causal flash attention (UNCHANGED from R16, passing). QKV [8192,3072] bf16,
// Q pre-scaled by 0.125*log2(e). Merged q-groups, dbuf K/V, V slot-permuted so
// PV A-frag assembles directly from cvt_pk outputs (no P LDS round-trip).
__global__ __launch_bounds__(256, 2) void attn_fwd(const ushort_t* __restrict__ QKV,
                                                   ushort_t* __restrict__ ctx) {
  const int bid = blockIdx.x;
  const int h = bid & 15;
  const int b = (bid >> 4) & 7;
  const int p = bid >> 7;  // 0..3
  const int tid = threadIdx.x;
  const int lane = tid & 63;
  const int w = tid >> 6;
  const int lr = lane & 15;
  const int lg = lane >> 4;
  const int dk = lg << 3;

  __shared__ __attribute__((aligned(16))) ushort_t Ks[2][64 * 72];
  __shared__ __attribute__((aligned(16))) uint_t VtDw[2][64 * 36];

  const int kkey = tid >> 2, kdg = tid & 3;
  const int vkp = tid & 31, vdg = tid >> 5;
  const int pkp = ((vkp >> 4) << 4) | (((vkp >> 1) & 3) << 2) |
                  (((vkp >> 3) & 1) << 1) | (vkp & 1);
  const ushort_t* kgbase =
      QKV + ((size_t)(b * 1024 + kkey)) * 3072 + 1024 + h * 64 + kdg * 16;
  const ushort_t* vgbase =
      QKV + ((size_t)(b * 1024 + 2 * vkp)) * 3072 + 2048 + h * 64 + vdg * 8;

  const float FMAX2 = 23.083120654223414f;  // 16 * log2(e)

  const int qtA = p, qtB = 7 - p;
  const int ntB = (qtB + 1) << 1;
  const int wrow0A = (qtA << 7) + w * 32;
  const int wrow0B = (qtB << 7) + w * 32;

  bf16x8 qfA[2][2], qfB[2][2];
#pragma unroll
  for (int i = 0; i < 2; ++i) {
    const ushort_t* qpA =
        QKV + ((size_t)(b * 1024 + wrow0A + i * 16 + lr)) * 3072 + h * 64 + dk;
    qfA[i][0] = *reinterpret_cast<const bf16x8*>(qpA);
    qfA[i][1] = *reinterpret_cast<const bf16x8*>(qpA + 32);
    const ushort_t* qpB =
        QKV + ((size_t)(b * 1024 + wrow0B + i * 16 + lr)) * 3072 + h * 64 + dk;
    qfB[i][0] = *reinterpret_cast<const bf16x8*>(qpB);
    qfB[i][1] = *reinterpret_cast<const bf16x8*>(qpB + 32);
  }

  f32x4 oA[2][4] = {}, oB[2][4] = {};
  float lsA[2] = {0.f, 0.f}, lsB[2] = {0.f, 0.f};

  uint4 rk0 = *reinterpret_cast<const uint4*>(kgbase);
  uint4 rk1 = *reinterpret_cast<const uint4*>(kgbase + 8);
  uint4 rv0 = *reinterpret_cast<const uint4*>(vgbase);
  uint4 rv1 = *reinterpret_cast<const uint4*>(vgbase + 3072);

  for (int t = 0; t < ntB; ++t) {
    const int bsel = t & 1;
    asm volatile("s_waitcnt vmcnt(0)" ::: "memory");
    {
      uint_t* kd = reinterpret_cast<uint_t*>(&Ks[bsel][kkey * 72 + kdg * 16]);
      *reinterpret_cast<uint4*>(kd) = rk0;
      *reinterpret_cast<uint4*>(kd + 4) = rk1;
      const ushort_t* e0 = reinterpret_cast<const ushort_t*>(&rv0);
      const ushort_t* e1 = reinterpret_cast<const ushort_t*>(&rv1);
#pragma unroll
      for (int j = 0; j < 8; ++j)
        VtDw[bsel][(vdg * 8 + j) * 36 + pkp] = (uint_t)e0[j] | ((uint_t)e1[j] << 16);
    }
    if (t + 1 < ntB) {
      const size_t off = (size_t)(t + 1) * 64 * 3072;
      rk0 = *reinterpret_cast<const uint4*>(kgbase + off);
      rk1 = *reinterpret_cast<const uint4*>(kgbase + off + 8);
      rv0 = *reinterpret_cast<const uint4*>(vgbase + off);
      rv1 = *reinterpret_cast<const uint4*>(vgbase + off + 3072);
    }
    asm volatile("s_waitcnt lgkmcnt(0)" ::: "memory");
    __builtin_amdgcn_s_barrier();

    const int kb = t << 6;
    const bool actB = (kb <= wrow0B + 31);
    const bool actA = (kb <= wrow0A + 31);
    if (!(actA || actB)) continue;

    bf16x8 kf0[4], kf1[4];
#pragma unroll
    for (int f = 0; f < 4; ++f) {
      kf0[f] = *reinterpret_cast<const bf16x8*>(&Ks[bsel][(f * 16 + lr) * 72 + dk]);
      kf1[f] =
          *reinterpret_cast<const bf16x8*>(&Ks[bsel][(f * 16 + lr) * 72 + 32 + dk]);
    }
    bf16x8 vb[2][4];
#pragma unroll
    for (int kblk = 0; kblk < 2; ++kblk)
#pragma unroll
      for (int fh = 0; fh < 4; ++fh)
        vb[kblk][fh] = *reinterpret_cast<const bf16x8*>(
            &VtDw[bsel][(fh * 16 + lr) * 36 + kblk * 16 + (lg << 2)]);

    auto group = [&](const bf16x8(&qf)[2][2], f32x4(&o)[2][4], float(&ls)[2],
                     int wrow0) __attribute__((always_inline)) {
      f32x4 s[2][4];
      __builtin_amdgcn_s_setprio(1);
#pragma unroll
      for (int i = 0; i < 2; ++i)
#pragma unroll
        for (int f = 0; f < 4; ++f) {
          f32x4 z = {0.f, 0.f, 0.f, 0.f};
          z = __builtin_amdgcn_mfma_f32_16x16x32_bf16(kf0[f], qf[i][0], z, 0, 0, 0);
          s[i][f] = __builtin_amdgcn_mfma_f32_16x16x32_bf16(kf1[f], qf[i][1], z, 0, 0, 0);
        }
      __builtin_amdgcn_s_setprio(0);
      const bool needmask = (kb + 63 > wrow0);
#pragma unroll
      for (int i = 0; i < 2; ++i) {
        const int qr = wrow0 + i * 16 + lr;
        uint_t d0[4], d1[4];
#pragma unroll
        for (int f = 0; f < 4; ++f) {
          const int kbase = kb + f * 16 + (lg << 2);
          float p0 = __builtin_amdgcn_exp2f(s[i][f][0] - FMAX2);
          float p1 = __builtin_amdgcn_exp2f(s[i][f][1] - FMAX2);
          float p2 = __builtin_amdgcn_exp2f(s[i][f][2] - FMAX2);
          float p3 = __builtin_amdgcn_exp2f(s[i][f][3] - FMAX2);
          if (needmask) {
            p0 = (kbase + 0 <= qr) ? p0 : 0.f;
            p1 = (kbase + 1 <= qr) ? p1 : 0.f;
            p2 = (kbase + 2 <= qr) ? p2 : 0.f;
            p3 = (kbase + 3 <= qr) ? p3 : 0.f;
          }
          ls[i] += (p0 + p1) + (p2 + p3);
          asm("v_cvt_pk_bf16_f32 %0, %1, %2" : "=v"(d0[f]) : "v"(p0), "v"(p1));
          asm("v_cvt_pk_bf16_f32 %0, %1, %2" : "=v"(d1[f]) : "v"(p2), "v"(p3));
        }
        __builtin_amdgcn_s_setprio(1);
#pragma unroll
        for (int kblk = 0; kblk < 2; ++kblk) {
          uint4 paw;
          paw.x = d0[2 * kblk];
          paw.y = d1[2 * kblk];
          paw.z = d0[2 * kblk + 1];
          paw.w = d1[2 * kblk + 1];
          const bf16x8 pa = __builtin_bit_cast(bf16x8, paw);
#pragma unroll
          for (int fh = 0; fh < 4; ++fh)
            o[i][fh] = __builtin_amdgcn_mfma_f32_16x16x32_bf16(pa, vb[kblk][fh],
                                                               o[i][fh], 0, 0, 0);
        }
        __builtin_amdgcn_s_setprio(0);
      }
    };

    if (actB) group(qfB, oB, lsB, wrow0B);
    if (actA) group(qfA, oA, lsA, wrow0A);
  }

  auto epi = [&](f32x4(&o)[2][4], float(&ls)[2], int wrow0)
      __attribute__((always_inline)) {
#pragma unroll
    for (int i = 0; i < 2; ++i) {
      float s = ls[i];
      s += __shfl_xor(s, 16);
      s += __shfl_xor(s, 32);
      const float linv = 1.0f / s;
      const size_t crow = (size_t)(b * 1024 + wrow0 + i * 16 + (lg << 2));
#pragma unroll
      for (int r = 0; r < 4; ++r) {
        const float li = __shfl(linv, (lg << 2) + r);
#pragma unroll
        for (int fh = 0; fh < 4; ++fh)
          ctx[(crow + r) * 1024 + h * 64 + fh * 16 + lr] = f2bf(o[i][fh][r] * li);
      }
    }
  };
  epi(oB, lsB, wrow0B);
  epi(oA, lsA, wrow0A);
}

extern "C" void kernel_launch(void* const* d_in, const int* in_sizes, int n_in,
                              void* d_out, int out_size, void* d_ws, size_t ws_size,
                              hipStream_t stream) {
  const float* x = (const float*)d_in[0];
  const float* Wk = (const float*)d_in[1];
  const float* Wq = (const float*)d_in[2];
  const float* Wv = (const float*)d_in[3];
  const float* Wo = (const float*)d_in[4];

  char* ws = (char*)d_ws;
  ushort_t* xb = (ushort_t*)ws;                  // [8192,1024] bf16 (reused as ctx)
  ushort_t* Wc = (ushort_t*)(ws + (16u << 20));  // Wq*0.125*log2e | Wk | Wv | Wo
  ushort_t* Wob = Wc + 3u * 1024 * 1024;
  ushort_t* QKV = (ushort_t*)(ws + (24u << 20));  // [8192,3072] bf16
  ushort_t* ctx = xb;

  // All casts in one launch: 3M float4 units.
  cast_all<<<12288, 256, 0, stream>>>(x, Wq, Wk, Wv, Wo, xb, Wc,
                                      0.125f * 1.4426950408889634f);

  // QKV: BM=256, BN=192 (R12 geometry + R17 overlap schedule).
  gemm8p<8, 3, 16, 3072, false><<<512, 512, 0, stream>>>(xb, Wc, QKV);

  attn_fwd<<<512, 256, 0, stream>>>(QKV, ctx);

  // Out-proj: BM=128, BN=128 (R14 geometry + R17 overlap schedule).
  gemm8p<4, 2, 8, 1024, true><<<512, 512, 0, stream>>>(ctx, Wob, (float*)d_out);
}